// Round 9
// baseline (198.449 us; speedup 1.0000x reference)
//
#include <hip/hip_runtime.h>
#include <hip/hip_bf16.h>

// ConvSelfAttentionModule: B=4, C=256, CQK=128, N=4096 (64x64), fp32 in/out.
// R17 = R16 (proven 178.4us) + c-split k_fav for 2 wgs/CU TLP.
// k_fav was 63us at 1 wg/CU: per-iter serial QK->exp->barrier->AV chain
// (~2360 cyc) vs ~430 cyc of issue work; nothing on the CU to overlap it.
// Fix: 512 wgs, each owns c-half [ch*128,+128) of the SAME 64-j block. QK/sE
// phase duplicated per pair (8 of 24 MFMA) but wave assignment, sE geometry,
// swizzle, and barrier structure are BYTE-IDENTICAL to the thrice-proven R4
// body; only vtb base, vf/acc extents, AV mt-loop, epilogue c, and the grid
// decode change (all deterministic indexing). VGPR ~84->~70 -> 2 wgs/CU
// co-resident -> two independent barrier groups per CU: one wg's AV-MFMA
// overlaps the other's exp/VALU.
//   frag-tile addressing (16 rows x 32 k per 1KB tile, lane-major):
//     tile elem addr = tile*T + ks*512 + quad*128 + col*8 + e
//   k_wcvt   : W -> f16 fragment-tiled [R16]
//   k_xsplit : x -> fragment-tiled f16 [R16]
//   k_proj   : register-direct projections, no LDS/barriers [R16]
//   k_rows   : QK^T + exp + partial row sums (widened, 128 j/wg) [R15]
//   k_rsum   : rinv[b][i] = 1 / sum_j exp(S[i,j]) [R15]
//   k_fav    : fused recompute+AV, c-split (above)

typedef _Float16 f16;
typedef _Float16 f16x4v __attribute__((ext_vector_type(4)));
typedef _Float16 f16x8v __attribute__((ext_vector_type(8)));
typedef float f32x4v __attribute__((ext_vector_type(4)));

static __device__ __forceinline__ f32x4v mfma16(f16x8v a, f16x8v b, f32x4v c) {
  // A-frag m=lane&15,k=quad*8+e; B-frag n=lane&15,k=quad*8+e
  // D: col(n)=lane&15, row(m)=quad*4+reg
  return __builtin_amdgcn_mfma_f32_16x16x32_f16(a, b, c, 0, 0, 0);
}

// ---------------- kernel 0a: weight convert -> fragment-tiled ----------------
// wT elem (o,c): (o>>4)*4096 + (c>>5)*512 + ((c>>3)&3)*128 + (o&15)*8 + (c&7)
__global__ void k_wcvt(const float* __restrict__ wq, const float* __restrict__ bq,
                       const float* __restrict__ wk, const float* __restrict__ bk,
                       const float* __restrict__ wv, const float* __restrict__ bv,
                       f16* __restrict__ wh, float* __restrict__ bcat) {
  int o = blockIdx.x;          // 512 rows: 0-127 q, 128-255 k, 256-511 v
  int c = threadIdx.x;         // 256
  const float* wrow; float bias;
  if (o < 128)      { wrow = wq + (size_t)o * 256;         bias = bq[o]; }
  else if (o < 256) { wrow = wk + (size_t)(o - 128) * 256; bias = bk[o - 128]; }
  else              { wrow = wv + (size_t)(o - 256) * 256; bias = bv[o - 256]; }
  wh[(size_t)(o >> 4) * 4096 + (size_t)(c >> 5) * 512 +
     (size_t)((c >> 3) & 3) * 128 + (o & 15) * 8 + (c & 7)] = (f16)wrow[c];
  if (c == 0) bcat[o] = bias;
}

// ---------------- kernel 0b: x transpose -> fragment-tiled f16 ----------------
// xTf elem (t,c): b*1048576 + (t>>4)*4096 + (c>>5)*512 + ((c>>3)&3)*128
//                 + (t&15)*8 + (c&7)
__global__ void k_xsplit(const float* __restrict__ x, f16* __restrict__ xh) {
  __shared__ float t[64][65];
  int b = blockIdx.z, c0 = blockIdx.y * 64, n0 = blockIdx.x * 64;
  int tx = threadIdx.x & 63, ty = threadIdx.x >> 6;
  const float* xb = x + ((size_t)b * 256 + c0) * 4096 + n0;
#pragma unroll
  for (int r = ty; r < 64; r += 4) t[r][tx] = xb[(size_t)r * 4096 + tx];
  __syncthreads();
  f16* xbb = xh + (size_t)b * 1048576;
#pragma unroll
  for (int k2 = 0; k2 < 2; k2++) {
    int id = k2 * 256 + threadIdx.x;
    int tok = id & 63, oct = id >> 6;          // oct = 8-channel group 0..7
    int tt = n0 + tok;
    f16x8v v;
#pragma unroll
    for (int e = 0; e < 8; e++) v[e] = (f16)t[oct * 8 + e][tok];
    size_t addr = (size_t)(tt >> 4) * 4096 +
                  (size_t)((c0 >> 5) + (oct >> 2)) * 512 +
                  (size_t)(oct & 3) * 128 + (tt & 15) * 8;
    *(f16x8v*)&xbb[addr] = v;
  }
}

// ---------------- kernel 1: projections, register-direct [R16] ----------------
__global__ void __launch_bounds__(512, 1)
k_proj(const f16* __restrict__ xh, const f16* __restrict__ wh,
       const float* __restrict__ bcat, f16* __restrict__ qT,
       f16* __restrict__ kT, f16* __restrict__ vT) {
  int ob = blockIdx.x, th = blockIdx.y, b = blockIdx.z;
  int tid = threadIdx.x, l = tid & 63, w = tid >> 6;
  int col = l & 15, quad = l >> 4;
  int tt = w & 3, oh = w >> 2;
  int OT0 = ob * 4 + oh * 2;                   // first of 2 resident o-tiles
  const f16* wtb = wh + (size_t)OT0 * 4096 + l * 8;
  f16x8v wb[2][8];
#pragma unroll
  for (int jt = 0; jt < 2; jt++)
#pragma unroll
    for (int ks = 0; ks < 8; ks++)
      wb[jt][ks] = *(const f16x8v*)(wtb + jt * 4096 + ks * 512);
  float bias0 = bcat[OT0 * 16 + col];
  float bias1 = bcat[OT0 * 16 + 16 + col];
  const f16* atb = xh + (size_t)b * 1048576 + (size_t)(th * 32 + tt) * 4096 + l * 8;
  f16x8v afA[8], afB[8];
#pragma unroll
  for (int ks = 0; ks < 8; ks++) afA[ks] = *(const f16x8v*)(atb + ks * 512);

#define PROJ_BODY(IT, AF, AN, PREF)                                            \
  {                                                                            \
    if (PREF) {                                                                \
      _Pragma("unroll") for (int ks = 0; ks < 8; ks++)                         \
        AN[ks] = *(const f16x8v*)(atb + (size_t)((IT) + 1) * 16384 + ks * 512);\
    }                                                                          \
    f32x4v s0 = {}, s1 = {};                                                   \
    _Pragma("unroll") for (int ks = 0; ks < 8; ks++) {                         \
      s0 = mfma16(AF[ks], wb[0][ks], s0);                                      \
      s1 = mfma16(AF[ks], wb[1][ks], s1);                                      \
    }                                                                          \
    int T = th * 32 + (IT) * 4 + tt;                                           \
    if (ob < 4) {                                                              \
      f16* dst = (ob < 2) ? qT : kT;                                           \
      _Pragma("unroll") for (int jt = 0; jt < 2; jt++) {                       \
        int o = OT0 * 16 + jt * 16 + col;                                      \
        int d = o & 127;                                                       \
        float bs = jt ? bias1 : bias0;                                         \
        size_t base = (size_t)b * 524288 + (size_t)T * 2048 +                  \
                      (size_t)(d >> 5) * 512 + (size_t)((d >> 3) & 3) * 128 +  \
                      (d & 7);                                                 \
        float sv0 = jt ? s1[0] : s0[0], sv1 = jt ? s1[1] : s0[1];              \
        float sv2 = jt ? s1[2] : s0[2], sv3 = jt ? s1[3] : s0[3];              \
        dst[base + (quad * 4 + 0) * 8] = (f16)(sv0 + bs);                      \
        dst[base + (quad * 4 + 1) * 8] = (f16)(sv1 + bs);                      \
        dst[base + (quad * 4 + 2) * 8] = (f16)(sv2 + bs);                      \
        dst[base + (quad * 4 + 3) * 8] = (f16)(sv3 + bs);                      \
      }                                                                        \
    } else {                                                                   \
      int i0 = T * 16 + quad * 4;                                              \
      size_t ibase = (size_t)b * 1048576 + (size_t)(i0 >> 5) * 512 +           \
                     (size_t)((i0 >> 3) & 3) * 128 + (i0 & 7);                 \
      _Pragma("unroll") for (int jt = 0; jt < 2; jt++) {                       \
        int c = OT0 * 16 + jt * 16 + col - 256;                                \
        float bs = jt ? bias1 : bias0;                                         \
        f16x4v pv;                                                             \
        _Pragma("unroll") for (int rg = 0; rg < 4; rg++)                       \
          pv[rg] = (f16)((jt ? s1[rg] : s0[rg]) + bs);                         \
        *(f16x4v*)&vT[ibase + (size_t)(c >> 4) * 65536 + (c & 15) * 8] = pv;   \
      }                                                                        \
    }                                                                          \
  }

  for (int itp = 0; itp < 4; itp++) {
    int itA = itp * 2;
    PROJ_BODY(itA, afA, afB, true)
    PROJ_BODY(itA + 1, afB, afA, itp < 3)
  }
#undef PROJ_BODY
}

// ---------------- kernel 2: row sums of exp(S), widened (128 j per wg) [R15] ----------------
__global__ void __launch_bounds__(512, 2)
k_rows(const f16* __restrict__ qT, const f16* __restrict__ kT,
       float* __restrict__ partial) {
  int jblk = blockIdx.x, ih = blockIdx.y, b = blockIdx.z;
  int tid = threadIdx.x, l = tid & 63, w = tid >> 6;
  int col = l & 15;
  int ti = w & 3, jh = w >> 2;
  const f16* ktb = kT + (size_t)b * 524288 + (size_t)(jblk * 8 + jh * 4) * 2048 + l * 8;
  const f16* qtb = qT + (size_t)b * 524288 + (size_t)ti * 2048 + l * 8;
  f16x8v ka[4][4];
#pragma unroll
  for (int jt = 0; jt < 4; jt++)
#pragma unroll
    for (int ks = 0; ks < 4; ks++)
      ka[jt][ks] = *(const f16x8v*)(ktb + jt * 2048 + ks * 512);
  float* pout = partial + ((size_t)(b * 32 + jblk) * 2 + jh) * 4096 + ti * 16 + col;
  int it0 = ih * 32;
  f16x8v qfA[4], qfB[4];
#pragma unroll
  for (int ks = 0; ks < 4; ks++)
    qfA[ks] = *(const f16x8v*)(qtb + (size_t)it0 * 8192 + ks * 512);

#define ROWS_BODY(IT, QF, QN, PREF)                                           \
  {                                                                           \
    if (PREF) {                                                               \
      _Pragma("unroll") for (int ks = 0; ks < 4; ks++)                        \
        QN[ks] = *(const f16x8v*)(qtb + (size_t)((IT) + 1) * 8192 + ks * 512);\
    }                                                                         \
    f32x4v s[4] = {};                                                         \
    _Pragma("unroll") for (int ks = 0; ks < 4; ks++) {                        \
      s[0] = mfma16(ka[0][ks], QF[ks], s[0]);                                 \
      s[1] = mfma16(ka[1][ks], QF[ks], s[1]);                                 \
      s[2] = mfma16(ka[2][ks], QF[ks], s[2]);                                 \
      s[3] = mfma16(ka[3][ks], QF[ks], s[3]);                                 \
    }                                                                         \
    float t = 0.f;                                                            \
    _Pragma("unroll") for (int jt = 0; jt < 4; jt++)                          \
      _Pragma("unroll") for (int rg = 0; rg < 4; rg++)                        \
        t += __expf(s[jt][rg]);                                               \
    t += __shfl_xor(t, 16);                                                   \
    t += __shfl_xor(t, 32);                                                   \
    if (l < 16) pout[(size_t)(IT) * 64] = t;                                  \
  }

  for (int itp = 0; itp < 16; itp++) {
    int itA = it0 + itp * 2;
    ROWS_BODY(itA, qfA, qfB, true)
    ROWS_BODY(itA + 1, qfB, qfA, itp < 15)
  }
#undef ROWS_BODY
}

// ---------------- kernel 3: combine partials -> rinv = 1/rowsum ----------------
__global__ void k_rsum(const float* __restrict__ partial, float* __restrict__ rinv) {
  int b = blockIdx.y;
  int i = blockIdx.x * 256 + threadIdx.x;
  const float* p = partial + (size_t)b * 64 * 4096 + i;
  float s = 0.f;
#pragma unroll 8
  for (int jb = 0; jb < 64; jb++) s += p[(size_t)jb * 4096];
  rinv[(size_t)b * 4096 + i] = 1.0f / s;
}

// ---------------- kernel 4: fused recompute + AV, c-split, 2 wgs/CU ----------------
// Per wg: batch b, j-cols [j0,j0+64), c-half [ch*128, ch*128+128). Loop i in
// 64-steps: S^T = mfma(K_regs, Q_regs); E' = exp(S)*rinv -> sE (dbuf,
// swizzled); acc[c][j] += mfma(V_regs, E'^T). QK wave roles, sE geometry,
// swizzle, barrier structure IDENTICAL to the proven R4 body; AV covers one
// c-tile per wave (vtb = c-tile ch*8+w).
__global__ void __launch_bounds__(512, 2)
k_fav(const f16* __restrict__ qT, const f16* __restrict__ kT,
      const f16* __restrict__ vT, const float* __restrict__ rinv,
      const float* __restrict__ x, const float* __restrict__ gamma,
      float* __restrict__ out) {
  __shared__ f16 sE[2][4096];   // [buf][64 j][64 i], 8-elem i-groups XOR(j&7)
  // XCD-chunked swizzle: 512 wgs, 8 XCDs -> contiguous 64-wg slice per XCD;
  // adjacent lg pairs share (b,j0), differ in ch -> shared K/Q L2 lines.
  int wg = blockIdx.x;
  int lg = (wg & 7) * 64 + (wg >> 3);
  int b = lg >> 7;
  int rem = lg & 127;
  int j0 = (rem >> 1) * 64;
  int ch = rem & 1;
  int tid = threadIdx.x, l = tid & 63, w = tid >> 6;
  int col = l & 15, quad = l >> 4;
  int ti = w & 3, tjb = (w >> 2) * 2;
  const f16* ktb = kT + (size_t)b * 524288 + (size_t)(j0 / 16 + tjb) * 2048 + l * 8;
  const f16* qtb = qT + (size_t)b * 524288 + (size_t)ti * 2048 + l * 8;
  const f16* vtb = vT + (size_t)b * 1048576 + (size_t)(ch * 8 + w) * 65536 + l * 8;
  const float* rp = rinv + (size_t)b * 4096 + ti * 16 + col;
  // K fragments: resident whole kernel
  f16x8v ka0[4], ka1[4];
#pragma unroll
  for (int ks = 0; ks < 4; ks++) {
    ka0[ks] = *(const f16x8v*)(ktb + ks * 512);
    ka1[ks] = *(const f16x8v*)(ktb + 2048 + ks * 512);
  }
  f16x8v qfA[4], qfB[4], vfA[2], vfB[2];
  float rvA, rvB;
#pragma unroll
  for (int ks = 0; ks < 4; ks++) qfA[ks] = *(const f16x8v*)(qtb + ks * 512);
#pragma unroll
  for (int ks = 0; ks < 2; ks++)
    vfA[ks] = *(const f16x8v*)(vtb + ks * 512);
  rvA = rp[0];
  f32x4v acc[4] = {};
  int ig = ti * 2 + (col >> 3);
  int i_lo = col & 7;

#define FAV_BODY(IT, QF, VF, RV, QN, VN, RN, PREF, SEB)                        \
  {                                                                            \
    if (PREF) {                                                                \
      _Pragma("unroll") for (int ks = 0; ks < 4; ks++)                         \
        QN[ks] = *(const f16x8v*)(qtb + (size_t)((IT) + 1) * 8192 + ks * 512); \
      _Pragma("unroll") for (int ks = 0; ks < 2; ks++)                         \
        VN[ks] = *(const f16x8v*)(vtb + (size_t)(((IT) + 1) * 2 + ks) * 512);  \
      RN = rp[((IT) + 1) * 64];                                                \
    }                                                                          \
    f32x4v s0 = {}, s1 = {};                                                   \
    _Pragma("unroll") for (int ks = 0; ks < 4; ks++) {                         \
      s0 = mfma16(ka0[ks], QF[ks], s0);                                        \
      s1 = mfma16(ka1[ks], QF[ks], s1);                                        \
    }                                                                          \
    _Pragma("unroll") for (int rg = 0; rg < 4; rg++) {                         \
      int jl0 = tjb * 16 + quad * 4 + rg;                                      \
      sE[SEB][jl0 * 64 + ((ig ^ (jl0 & 7)) * 8) + i_lo] = (f16)(__expf(s0[rg]) * RV); \
      sE[SEB][(jl0 + 16) * 64 + ((ig ^ (jl0 & 7)) * 8) + i_lo] = (f16)(__expf(s1[rg]) * RV); \
    }                                                                          \
    asm volatile("s_waitcnt lgkmcnt(0)\n\ts_barrier" ::: "memory");            \
    _Pragma("unroll") for (int ks = 0; ks < 2; ks++) {                         \
      int sw = ((ks * 4 + quad) ^ (col & 7)) * 8;                              \
      f16x8v e0 = *(const f16x8v*)&sE[SEB][col * 64 + sw];                     \
      f16x8v e1 = *(const f16x8v*)&sE[SEB][(16 + col) * 64 + sw];              \
      f16x8v e2 = *(const f16x8v*)&sE[SEB][(32 + col) * 64 + sw];              \
      f16x8v e3 = *(const f16x8v*)&sE[SEB][(48 + col) * 64 + sw];              \
      acc[0] = mfma16(VF[ks], e0, acc[0]);                                     \
      acc[1] = mfma16(VF[ks], e1, acc[1]);                                     \
      acc[2] = mfma16(VF[ks], e2, acc[2]);                                     \
      acc[3] = mfma16(VF[ks], e3, acc[3]);                                     \
    }                                                                          \
  }

  for (int itp = 0; itp < 32; itp++) {
    int itA = itp * 2;
    FAV_BODY(itA, qfA, vfA, rvA, qfB, vfB, rvB, true, 0)
    FAV_BODY(itA + 1, qfB, vfB, rvB, qfA, vfA, rvA, itp < 31, 1)
  }
#undef FAV_BODY

  float gm = gamma[0];
  const float* xb = x + (size_t)b * 256 * 4096;
  float* ob = out + (size_t)b * 256 * 4096;
#pragma unroll
  for (int jt = 0; jt < 4; jt++) {
    int c = ch * 128 + w * 16 + quad * 4;
    int j = j0 + jt * 16 + col;
#pragma unroll
    for (int rg = 0; rg < 4; rg++) {
      size_t off = (size_t)(c + rg) * 4096 + j;
      ob[off] = gm * acc[jt][rg] + xb[off];
    }
  }
}

extern "C" void kernel_launch(void* const* d_in, const int* in_sizes, int n_in,
                              void* d_out, int out_size, void* d_ws, size_t ws_size,
                              hipStream_t stream) {
  (void)in_sizes; (void)n_in; (void)out_size; (void)ws_size;
  const float* x  = (const float*)d_in[0];
  const float* wq = (const float*)d_in[1];
  const float* bq = (const float*)d_in[2];
  const float* wk = (const float*)d_in[3];
  const float* bk = (const float*)d_in[4];
  const float* wv = (const float*)d_in[5];
  const float* bv = (const float*)d_in[6];
  const float* gm = (const float*)d_in[7];
  float* out = (float*)d_out;

  char* ws = (char*)d_ws;
  f16*  xh = (f16*)ws;                          // 8 MB fragment-tiled x
  f16*  qT = (f16*)(ws + 8388608);              // 4 MB fragment-tiled Q
  f16*  kT = (f16*)(ws + 12582912);             // 4 MB fragment-tiled K
  f16*  vT = (f16*)(ws + 16777216);             // 8 MB fragment-tiled V
  f16*  wh = (f16*)(ws + 25165824);             // 256 KB fragment-tiled W
  float* bcat    = (float*)(ws + 25427968);     // 2 KB
  float* rinv    = (float*)(ws + 25430016);     // 64 KB
  float* partial = (float*)(ws + 25495552);     // 4 MB: [b][64][4096]

  hipLaunchKernelGGL(k_wcvt, dim3(512), dim3(256), 0, stream, wq, bq, wk, bk, wv, bv, wh, bcat);
  hipLaunchKernelGGL(k_xsplit, dim3(64, 4, 4), dim3(256), 0, stream, x, xh);
  hipLaunchKernelGGL(k_proj, dim3(8, 8, 4), dim3(512), 0, stream, xh, wh, bcat, qT, kT, vT);
  hipLaunchKernelGGL(k_rows, dim3(32, 2, 4), dim3(512), 0, stream, qT, kT, partial);
  hipLaunchKernelGGL(k_rsum, dim3(16, 4), dim3(256), 0, stream, partial, rinv);
  hipLaunchKernelGGL(k_fav, dim3(512), dim3(512), 0, stream, qT, kT, vT, rinv, x, gm, out);
}

// Round 10
// 180.916 us; speedup vs baseline: 1.0969x; 1.0969x over previous
//
#include <hip/hip_runtime.h>
#include <hip/hip_bf16.h>

// ConvSelfAttentionModule: B=4, C=256, CQK=128, N=4096 (64x64), fp32 in/out.
// R18 = R16 (proven 178.4us) + two non-duplicating changes:
//  (1) k_fav: 2 i-tiles per barrier (32 barriers, was 64). sE = 2 pairs x 2
//      tiles (32KB); pair alternates per super-iter -> WAR-safe by the same
//      inductive barrier argument as the proven dbuf. Per-tile wave roles,
//      swizzles, ds patterns byte-identical to the R4 body. Prefetch
//      re-phased (V before QK, Q/rv after barrier) so no register doubling.
//      launch_bounds(512,1): grid=256=1 wg/CU anyway; avoids cap-spill.
//  (2) k_rows: 4-way i-split (512 wgs, 2/CU) to hide exp/store latency.
// R9 lesson (c-split, reverted): TLP bought by duplicating the serial QK/exp
// phase is net-negative (+33% MFMA, util didn't scale).
//   k_wcvt   : W -> f16 fragment-tiled [R16]
//   k_xsplit : x -> fragment-tiled f16 [R16]
//   k_proj   : register-direct projections, no LDS/barriers [R16]
//   k_rows   : QK^T + exp + partial row sums, 512 wgs
//   k_rsum   : rinv[b][i] = 1 / sum_j exp(S[i,j])
//   k_fav    : fused recompute+AV, 2-tile super-iters

typedef _Float16 f16;
typedef _Float16 f16x4v __attribute__((ext_vector_type(4)));
typedef _Float16 f16x8v __attribute__((ext_vector_type(8)));
typedef float f32x4v __attribute__((ext_vector_type(4)));

static __device__ __forceinline__ f32x4v mfma16(f16x8v a, f16x8v b, f32x4v c) {
  // A-frag m=lane&15,k=quad*8+e; B-frag n=lane&15,k=quad*8+e
  // D: col(n)=lane&15, row(m)=quad*4+reg
  return __builtin_amdgcn_mfma_f32_16x16x32_f16(a, b, c, 0, 0, 0);
}

// ---------------- kernel 0a: weight convert -> fragment-tiled ----------------
// wT elem (o,c): (o>>4)*4096 + (c>>5)*512 + ((c>>3)&3)*128 + (o&15)*8 + (c&7)
__global__ void k_wcvt(const float* __restrict__ wq, const float* __restrict__ bq,
                       const float* __restrict__ wk, const float* __restrict__ bk,
                       const float* __restrict__ wv, const float* __restrict__ bv,
                       f16* __restrict__ wh, float* __restrict__ bcat) {
  int o = blockIdx.x;          // 512 rows: 0-127 q, 128-255 k, 256-511 v
  int c = threadIdx.x;         // 256
  const float* wrow; float bias;
  if (o < 128)      { wrow = wq + (size_t)o * 256;         bias = bq[o]; }
  else if (o < 256) { wrow = wk + (size_t)(o - 128) * 256; bias = bk[o - 128]; }
  else              { wrow = wv + (size_t)(o - 256) * 256; bias = bv[o - 256]; }
  wh[(size_t)(o >> 4) * 4096 + (size_t)(c >> 5) * 512 +
     (size_t)((c >> 3) & 3) * 128 + (o & 15) * 8 + (c & 7)] = (f16)wrow[c];
  if (c == 0) bcat[o] = bias;
}

// ---------------- kernel 0b: x transpose -> fragment-tiled f16 ----------------
// xTf elem (t,c): b*1048576 + (t>>4)*4096 + (c>>5)*512 + ((c>>3)&3)*128
//                 + (t&15)*8 + (c&7)
__global__ void k_xsplit(const float* __restrict__ x, f16* __restrict__ xh) {
  __shared__ float t[64][65];
  int b = blockIdx.z, c0 = blockIdx.y * 64, n0 = blockIdx.x * 64;
  int tx = threadIdx.x & 63, ty = threadIdx.x >> 6;
  const float* xb = x + ((size_t)b * 256 + c0) * 4096 + n0;
#pragma unroll
  for (int r = ty; r < 64; r += 4) t[r][tx] = xb[(size_t)r * 4096 + tx];
  __syncthreads();
  f16* xbb = xh + (size_t)b * 1048576;
#pragma unroll
  for (int k2 = 0; k2 < 2; k2++) {
    int id = k2 * 256 + threadIdx.x;
    int tok = id & 63, oct = id >> 6;          // oct = 8-channel group 0..7
    int tt = n0 + tok;
    f16x8v v;
#pragma unroll
    for (int e = 0; e < 8; e++) v[e] = (f16)t[oct * 8 + e][tok];
    size_t addr = (size_t)(tt >> 4) * 4096 +
                  (size_t)((c0 >> 5) + (oct >> 2)) * 512 +
                  (size_t)(oct & 3) * 128 + (tt & 15) * 8;
    *(f16x8v*)&xbb[addr] = v;
  }
}

// ---------------- kernel 1: projections, register-direct [R16] ----------------
__global__ void __launch_bounds__(512, 1)
k_proj(const f16* __restrict__ xh, const f16* __restrict__ wh,
       const float* __restrict__ bcat, f16* __restrict__ qT,
       f16* __restrict__ kT, f16* __restrict__ vT) {
  int ob = blockIdx.x, th = blockIdx.y, b = blockIdx.z;
  int tid = threadIdx.x, l = tid & 63, w = tid >> 6;
  int col = l & 15, quad = l >> 4;
  int tt = w & 3, oh = w >> 2;
  int OT0 = ob * 4 + oh * 2;                   // first of 2 resident o-tiles
  const f16* wtb = wh + (size_t)OT0 * 4096 + l * 8;
  f16x8v wb[2][8];
#pragma unroll
  for (int jt = 0; jt < 2; jt++)
#pragma unroll
    for (int ks = 0; ks < 8; ks++)
      wb[jt][ks] = *(const f16x8v*)(wtb + jt * 4096 + ks * 512);
  float bias0 = bcat[OT0 * 16 + col];
  float bias1 = bcat[OT0 * 16 + 16 + col];
  const f16* atb = xh + (size_t)b * 1048576 + (size_t)(th * 32 + tt) * 4096 + l * 8;
  f16x8v afA[8], afB[8];
#pragma unroll
  for (int ks = 0; ks < 8; ks++) afA[ks] = *(const f16x8v*)(atb + ks * 512);

#define PROJ_BODY(IT, AF, AN, PREF)                                            \
  {                                                                            \
    if (PREF) {                                                                \
      _Pragma("unroll") for (int ks = 0; ks < 8; ks++)                         \
        AN[ks] = *(const f16x8v*)(atb + (size_t)((IT) + 1) * 16384 + ks * 512);\
    }                                                                          \
    f32x4v s0 = {}, s1 = {};                                                   \
    _Pragma("unroll") for (int ks = 0; ks < 8; ks++) {                         \
      s0 = mfma16(AF[ks], wb[0][ks], s0);                                      \
      s1 = mfma16(AF[ks], wb[1][ks], s1);                                      \
    }                                                                          \
    int T = th * 32 + (IT) * 4 + tt;                                           \
    if (ob < 4) {                                                              \
      f16* dst = (ob < 2) ? qT : kT;                                           \
      _Pragma("unroll") for (int jt = 0; jt < 2; jt++) {                       \
        int o = OT0 * 16 + jt * 16 + col;                                      \
        int d = o & 127;                                                       \
        float bs = jt ? bias1 : bias0;                                         \
        size_t base = (size_t)b * 524288 + (size_t)T * 2048 +                  \
                      (size_t)(d >> 5) * 512 + (size_t)((d >> 3) & 3) * 128 +  \
                      (d & 7);                                                 \
        float sv0 = jt ? s1[0] : s0[0], sv1 = jt ? s1[1] : s0[1];              \
        float sv2 = jt ? s1[2] : s0[2], sv3 = jt ? s1[3] : s0[3];              \
        dst[base + (quad * 4 + 0) * 8] = (f16)(sv0 + bs);                      \
        dst[base + (quad * 4 + 1) * 8] = (f16)(sv1 + bs);                      \
        dst[base + (quad * 4 + 2) * 8] = (f16)(sv2 + bs);                      \
        dst[base + (quad * 4 + 3) * 8] = (f16)(sv3 + bs);                      \
      }                                                                        \
    } else {                                                                   \
      int i0 = T * 16 + quad * 4;                                              \
      size_t ibase = (size_t)b * 1048576 + (size_t)(i0 >> 5) * 512 +           \
                     (size_t)((i0 >> 3) & 3) * 128 + (i0 & 7);                 \
      _Pragma("unroll") for (int jt = 0; jt < 2; jt++) {                       \
        int c = OT0 * 16 + jt * 16 + col - 256;                                \
        float bs = jt ? bias1 : bias0;                                         \
        f16x4v pv;                                                             \
        _Pragma("unroll") for (int rg = 0; rg < 4; rg++)                       \
          pv[rg] = (f16)((jt ? s1[rg] : s0[rg]) + bs);                         \
        *(f16x4v*)&vT[ibase + (size_t)(c >> 4) * 65536 + (c & 15) * 8] = pv;   \
      }                                                                        \
    }                                                                          \
  }

  for (int itp = 0; itp < 4; itp++) {
    int itA = itp * 2;
    PROJ_BODY(itA, afA, afB, true)
    PROJ_BODY(itA + 1, afB, afA, itp < 3)
  }
#undef PROJ_BODY
}

// ---------------- kernel 2: row sums of exp(S), 512 wgs (2/CU) ----------------
// wg = (jblk [0,32), ih [0,4), b), 512 thr. Wave (ti=w&3, jh=w>>2): holds
// FOUR K j-tiles resident; 16 i-iters, Q frags dbuf-prefetched; 16 MFMA per
// 4 Q-loads. partial[b][jblk*2+jh][i] = sum over 64 j of exp. No LDS/barriers.
// 4-way ih split -> 2 wgs/CU, hides exp/store latency (i-ranges disjoint).
__global__ void __launch_bounds__(512, 2)
k_rows(const f16* __restrict__ qT, const f16* __restrict__ kT,
       float* __restrict__ partial) {
  int jblk = blockIdx.x, ih = blockIdx.y, b = blockIdx.z;
  int tid = threadIdx.x, l = tid & 63, w = tid >> 6;
  int col = l & 15;
  int ti = w & 3, jh = w >> 2;
  const f16* ktb = kT + (size_t)b * 524288 + (size_t)(jblk * 8 + jh * 4) * 2048 + l * 8;
  const f16* qtb = qT + (size_t)b * 524288 + (size_t)ti * 2048 + l * 8;
  f16x8v ka[4][4];
#pragma unroll
  for (int jt = 0; jt < 4; jt++)
#pragma unroll
    for (int ks = 0; ks < 4; ks++)
      ka[jt][ks] = *(const f16x8v*)(ktb + jt * 2048 + ks * 512);
  float* pout = partial + ((size_t)(b * 32 + jblk) * 2 + jh) * 4096 + ti * 16 + col;
  int it0 = ih * 16;
  f16x8v qfA[4], qfB[4];
#pragma unroll
  for (int ks = 0; ks < 4; ks++)
    qfA[ks] = *(const f16x8v*)(qtb + (size_t)it0 * 8192 + ks * 512);

#define ROWS_BODY(IT, QF, QN, PREF)                                           \
  {                                                                           \
    if (PREF) {                                                               \
      _Pragma("unroll") for (int ks = 0; ks < 4; ks++)                        \
        QN[ks] = *(const f16x8v*)(qtb + (size_t)((IT) + 1) * 8192 + ks * 512);\
    }                                                                         \
    f32x4v s[4] = {};                                                         \
    _Pragma("unroll") for (int ks = 0; ks < 4; ks++) {                        \
      s[0] = mfma16(ka[0][ks], QF[ks], s[0]);                                 \
      s[1] = mfma16(ka[1][ks], QF[ks], s[1]);                                 \
      s[2] = mfma16(ka[2][ks], QF[ks], s[2]);                                 \
      s[3] = mfma16(ka[3][ks], QF[ks], s[3]);                                 \
    }                                                                         \
    float t = 0.f;                                                            \
    _Pragma("unroll") for (int jt = 0; jt < 4; jt++)                          \
      _Pragma("unroll") for (int rg = 0; rg < 4; rg++)                        \
        t += __expf(s[jt][rg]);                                               \
    t += __shfl_xor(t, 16);                                                   \
    t += __shfl_xor(t, 32);                                                   \
    if (l < 16) pout[(size_t)(IT) * 64] = t;                                  \
  }

  for (int itp = 0; itp < 8; itp++) {
    int itA = it0 + itp * 2;
    ROWS_BODY(itA, qfA, qfB, true)
    ROWS_BODY(itA + 1, qfB, qfA, itp < 7)
  }
#undef ROWS_BODY
}

// ---------------- kernel 3: combine partials -> rinv = 1/rowsum ----------------
__global__ void k_rsum(const float* __restrict__ partial, float* __restrict__ rinv) {
  int b = blockIdx.y;
  int i = blockIdx.x * 256 + threadIdx.x;
  const float* p = partial + (size_t)b * 64 * 4096 + i;
  float s = 0.f;
#pragma unroll 8
  for (int jb = 0; jb < 64; jb++) s += p[(size_t)jb * 4096];
  rinv[(size_t)b * 4096 + i] = 1.0f / s;
}

// ---------------- kernel 4: fused recompute + AV, 2-tile super-iters ----------------
// Per wg: batch b, j-cols [j0,j0+64), all 256 c. Super-iter s (tiles t0=2s,
// t1=2s+1), pair p=s&1:
//   issue V(t0)->vfA, V(t1)->vfB                        (VMEM, used post-bar)
//   QK(t0) w/ qfA -> exp*rvA -> sE[p][0]                (R4 per-tile pattern)
//   QK(t1) w/ qfB -> exp*rvB -> sE[p][1]
//   lgkmcnt(0); s_barrier                               (ONE barrier / 2 tiles)
//   issue Q(t0+2)->qfA, Q(t1+2)->qfB, rv(t+2)           (covered by AV below)
//   AV(t0) from sE[p][0] w/ vfA; AV(t1) from sE[p][1] w/ vfB
// WAR: write pair p at s+2 vs read pair p at s separated by barrier(s+1);
// lgkmcnt(0) at each barrier drains both that wave's writes AND reads. Same
// inductive argument as the thrice-proven dbuf body.
__global__ void __launch_bounds__(512, 1)
k_fav(const f16* __restrict__ qT, const f16* __restrict__ kT,
      const f16* __restrict__ vT, const float* __restrict__ rinv,
      const float* __restrict__ x, const float* __restrict__ gamma,
      float* __restrict__ out) {
  __shared__ f16 sE[2][2][4096];  // [pair][tile][64 j][64 i], XOR(j&7) groups
  // XCD-chunked swizzle: 256 wgs, 8 XCDs -> contiguous 32-wg slice per XCD.
  int wg = blockIdx.x;
  int lg = (wg & 7) * 32 + (wg >> 3);
  int b = lg >> 6, j0 = (lg & 63) * 64;
  int tid = threadIdx.x, l = tid & 63, w = tid >> 6;
  int col = l & 15, quad = l >> 4;
  int ti = w & 3, tjb = (w >> 2) * 2;
  const f16* ktb = kT + (size_t)b * 524288 + (size_t)(j0 / 16 + tjb) * 2048 + l * 8;
  const f16* qtb = qT + (size_t)b * 524288 + (size_t)ti * 2048 + l * 8;
  const f16* vtb = vT + (size_t)b * 1048576 + (size_t)(w * 2) * 65536 + l * 8;
  const float* rp = rinv + (size_t)b * 4096 + ti * 16 + col;
  // K fragments: resident whole kernel
  f16x8v ka0[4], ka1[4];
#pragma unroll
  for (int ks = 0; ks < 4; ks++) {
    ka0[ks] = *(const f16x8v*)(ktb + ks * 512);
    ka1[ks] = *(const f16x8v*)(ktb + 2048 + ks * 512);
  }
  f16x8v qfA[4], qfB[4], vfA[2][2], vfB[2][2];
  float rvA, rvB;
#pragma unroll
  for (int ks = 0; ks < 4; ks++) {
    qfA[ks] = *(const f16x8v*)(qtb + ks * 512);
    qfB[ks] = *(const f16x8v*)(qtb + 8192 + ks * 512);
  }
  rvA = rp[0];
  rvB = rp[64];
  f32x4v acc[2][4] = {};
  int ig = ti * 2 + (col >> 3);
  int i_lo = col & 7;

#define FAV_QK(QF, RV, SEP, SET)                                               \
  {                                                                            \
    f32x4v s0 = {}, s1 = {};                                                   \
    _Pragma("unroll") for (int ks = 0; ks < 4; ks++) {                         \
      s0 = mfma16(ka0[ks], QF[ks], s0);                                        \
      s1 = mfma16(ka1[ks], QF[ks], s1);                                        \
    }                                                                          \
    _Pragma("unroll") for (int rg = 0; rg < 4; rg++) {                         \
      int jl0 = tjb * 16 + quad * 4 + rg;                                      \
      sE[SEP][SET][jl0 * 64 + ((ig ^ (jl0 & 7)) * 8) + i_lo] =                 \
          (f16)(__expf(s0[rg]) * RV);                                          \
      sE[SEP][SET][(jl0 + 16) * 64 + ((ig ^ (jl0 & 7)) * 8) + i_lo] =          \
          (f16)(__expf(s1[rg]) * RV);                                          \
    }                                                                          \
  }

#define FAV_AV(VF, SEP, SET)                                                   \
  {                                                                            \
    _Pragma("unroll") for (int ks = 0; ks < 2; ks++) {                         \
      int sw = ((ks * 4 + quad) ^ (col & 7)) * 8;                              \
      f16x8v e0 = *(const f16x8v*)&sE[SEP][SET][col * 64 + sw];                \
      f16x8v e1 = *(const f16x8v*)&sE[SEP][SET][(16 + col) * 64 + sw];         \
      f16x8v e2 = *(const f16x8v*)&sE[SEP][SET][(32 + col) * 64 + sw];         \
      f16x8v e3 = *(const f16x8v*)&sE[SEP][SET][(48 + col) * 64 + sw];         \
      acc[0][0] = mfma16(VF[0][ks], e0, acc[0][0]);                            \
      acc[0][1] = mfma16(VF[0][ks], e1, acc[0][1]);                            \
      acc[0][2] = mfma16(VF[0][ks], e2, acc[0][2]);                            \
      acc[0][3] = mfma16(VF[0][ks], e3, acc[0][3]);                            \
      acc[1][0] = mfma16(VF[1][ks], e0, acc[1][0]);                            \
      acc[1][1] = mfma16(VF[1][ks], e1, acc[1][1]);                            \
      acc[1][2] = mfma16(VF[1][ks], e2, acc[1][2]);                            \
      acc[1][3] = mfma16(VF[1][ks], e3, acc[1][3]);                            \
    }                                                                          \
  }

  for (int s = 0; s < 32; s++) {
    int t0 = s * 2;
    int p = s & 1;
    // V fragments for this super-iter's tiles (used after the barrier)
#pragma unroll
    for (int mt = 0; mt < 2; mt++)
#pragma unroll
      for (int ks = 0; ks < 2; ks++) {
        vfA[mt][ks] = *(const f16x8v*)(vtb + mt * 65536 + (size_t)(t0 * 2 + ks) * 512);
        vfB[mt][ks] = *(const f16x8v*)(vtb + mt * 65536 + (size_t)(t0 * 2 + 2 + ks) * 512);
      }
    if (p) { FAV_QK(qfA, rvA, 1, 0) FAV_QK(qfB, rvB, 1, 1) }
    else   { FAV_QK(qfA, rvA, 0, 0) FAV_QK(qfB, rvB, 0, 1) }
    asm volatile("s_waitcnt lgkmcnt(0)\n\ts_barrier" ::: "memory");
    if (s < 31) {
#pragma unroll
      for (int ks = 0; ks < 4; ks++) {
        qfA[ks] = *(const f16x8v*)(qtb + (size_t)(t0 + 2) * 8192 + ks * 512);
        qfB[ks] = *(const f16x8v*)(qtb + (size_t)(t0 + 3) * 8192 + ks * 512);
      }
      rvA = rp[(size_t)(t0 + 2) * 64];
      rvB = rp[(size_t)(t0 + 3) * 64];
    }
    if (p) { FAV_AV(vfA, 1, 0) FAV_AV(vfB, 1, 1) }
    else   { FAV_AV(vfA, 0, 0) FAV_AV(vfB, 0, 1) }
  }
#undef FAV_QK
#undef FAV_AV

  float gm = gamma[0];
  const float* xb = x + (size_t)b * 256 * 4096;
  float* ob = out + (size_t)b * 256 * 4096;
#pragma unroll
  for (int mt = 0; mt < 2; mt++)
#pragma unroll
    for (int jt = 0; jt < 4; jt++) {
      int c = w * 32 + mt * 16 + quad * 4;
      int j = j0 + jt * 16 + col;
#pragma unroll
      for (int rg = 0; rg < 4; rg++) {
        size_t off = (size_t)(c + rg) * 4096 + j;
        ob[off] = gm * acc[mt][jt][rg] + xb[off];
      }
    }
}

extern "C" void kernel_launch(void* const* d_in, const int* in_sizes, int n_in,
                              void* d_out, int out_size, void* d_ws, size_t ws_size,
                              hipStream_t stream) {
  (void)in_sizes; (void)n_in; (void)out_size; (void)ws_size;
  const float* x  = (const float*)d_in[0];
  const float* wq = (const float*)d_in[1];
  const float* bq = (const float*)d_in[2];
  const float* wk = (const float*)d_in[3];
  const float* bk = (const float*)d_in[4];
  const float* wv = (const float*)d_in[5];
  const float* bv = (const float*)d_in[6];
  const float* gm = (const float*)d_in[7];
  float* out = (float*)d_out;

  char* ws = (char*)d_ws;
  f16*  xh = (f16*)ws;                          // 8 MB fragment-tiled x
  f16*  qT = (f16*)(ws + 8388608);              // 4 MB fragment-tiled Q
  f16*  kT = (f16*)(ws + 12582912);             // 4 MB fragment-tiled K
  f16*  vT = (f16*)(ws + 16777216);             // 8 MB fragment-tiled V
  f16*  wh = (f16*)(ws + 25165824);             // 256 KB fragment-tiled W
  float* bcat    = (float*)(ws + 25427968);     // 2 KB
  float* rinv    = (float*)(ws + 25430016);     // 64 KB
  float* partial = (float*)(ws + 25495552);     // 4 MB: [b][64][4096]

  hipLaunchKernelGGL(k_wcvt, dim3(512), dim3(256), 0, stream, wq, bq, wk, bk, wv, bv, wh, bcat);
  hipLaunchKernelGGL(k_xsplit, dim3(64, 4, 4), dim3(256), 0, stream, x, xh);
  hipLaunchKernelGGL(k_proj, dim3(8, 8, 4), dim3(512), 0, stream, xh, wh, bcat, qT, kT, vT);
  hipLaunchKernelGGL(k_rows, dim3(32, 4, 4), dim3(512), 0, stream, qT, kT, partial);
  hipLaunchKernelGGL(k_rsum, dim3(16, 4), dim3(256), 0, stream, partial, rinv);
  hipLaunchKernelGGL(k_fav, dim3(256), dim3(512), 0, stream, qT, kT, vT, rinv, x, gm, out);
}